// Round 1
// baseline (43.100 us; speedup 1.0000x reference)
//
#include <hip/hip_runtime.h>

#define KC 256          // codebook size
#define DD 4            // vector dim
#define NROWS (8*64*64*64/4)   // 524288 rows of dim 4

// Prep: mh[k] = -0.5 * ||center_k||^2   (1 block, 256 threads)
__global__ void vq_prep(const float* __restrict__ center, float* __restrict__ mh) {
    int k = threadIdx.x;
    float4 c = reinterpret_cast<const float4*>(center)[k];
    mh[k] = -0.5f * (c.x * c.x + c.y * c.y + c.z * c.z + c.w * c.w);
}

// Main: per row, argmax_k (x . c_k - 0.5*||c_k||^2)  ==  argmin_k ||x - c_k||^2
// Output the hard-assigned center (forward value of the straight-through op).
template <bool USE_MH>
__global__ __launch_bounds__(256) void vq_main(const float* __restrict__ x,
                                               const float* __restrict__ center,
                                               const float* __restrict__ mh,
                                               float* __restrict__ out) {
    int row = blockIdx.x * 256 + threadIdx.x;
    float4 xv = reinterpret_cast<const float4*>(x)[row];

    const float4* c4 = reinterpret_cast<const float4*>(center);
    float bestp = -__builtin_inff();
    int bestk = 0;

#pragma unroll 8
    for (int k = 0; k < KC; ++k) {
        float4 c = c4[k];   // uniform -> scalar loads (s_load_dwordx4)
        float base;
        if (USE_MH) {
            base = mh[k];   // uniform -> s_load_dword
        } else {
            base = -0.5f * (c.x * c.x + c.y * c.y + c.z * c.z + c.w * c.w);
        }
        float p = fmaf(xv.x, c.x, base);
        p = fmaf(xv.y, c.y, p);
        p = fmaf(xv.z, c.z, p);
        p = fmaf(xv.w, c.w, p);
        if (p > bestp) { bestp = p; bestk = k; }   // strict '>' => first index wins ties
    }

    float4 cv = c4[bestk];  // divergent gather from 4KB table (L1-resident)
    reinterpret_cast<float4*>(out)[row] = cv;
}

extern "C" void kernel_launch(void* const* d_in, const int* in_sizes, int n_in,
                              void* d_out, int out_size, void* d_ws, size_t ws_size,
                              hipStream_t stream) {
    const float* x      = (const float*)d_in[0];
    const float* center = (const float*)d_in[1];
    float* out = (float*)d_out;

    if (ws_size >= KC * sizeof(float)) {
        float* mh = (float*)d_ws;
        vq_prep<<<1, KC, 0, stream>>>(center, mh);
        vq_main<true><<<NROWS / 256, 256, 0, stream>>>(x, center, mh, out);
    } else {
        vq_main<false><<<NROWS / 256, 256, 0, stream>>>(x, center, nullptr, out);
    }
}

// Round 2
// 28.608 us; speedup vs baseline: 1.5066x; 1.5066x over previous
//
#include <hip/hip_runtime.h>

#define KC 256                  // codebook size
#define NROWS (8*64*64*64/4)    // 524288 rows of dim 4
#define RPT 4                   // rows per thread
#define TPB 256                 // threads per block

// Per row: argmax_k (x . c_k - 0.5*||c_k||^2)  ==  argmin_k ||x - c_k||^2.
// Straight-through forward value is just the hard-assigned center.
__global__ __launch_bounds__(TPB) void vq_main(const float* __restrict__ x,
                                               const float* __restrict__ center,
                                               float* __restrict__ out) {
    __shared__ float4 sc[KC];   // codebook
    __shared__ float smh[KC];   // -0.5*||c||^2

    const int tid = threadIdx.x;
    {
        float4 c = reinterpret_cast<const float4*>(center)[tid];
        sc[tid] = c;
        smh[tid] = -0.5f * (c.x * c.x + c.y * c.y + c.z * c.z + c.w * c.w);
    }
    __syncthreads();

    const int base = blockIdx.x * (TPB * RPT) + tid;
    const float4* x4 = reinterpret_cast<const float4*>(x);

    float4 xv[RPT];
#pragma unroll
    for (int r = 0; r < RPT; ++r) xv[r] = x4[base + r * TPB];  // coalesced

    float bestp[RPT];
    int   bestk[RPT];
#pragma unroll
    for (int r = 0; r < RPT; ++r) { bestp[r] = -__builtin_inff(); bestk[r] = 0; }

#pragma unroll 8
    for (int k = 0; k < KC; ++k) {
        float4 c  = sc[k];      // uniform addr -> broadcast ds_read_b128
        float  mh = smh[k];     // uniform addr -> broadcast ds_read_b32
#pragma unroll
        for (int r = 0; r < RPT; ++r) {
            float p = fmaf(xv[r].x, c.x, mh);
            p = fmaf(xv[r].y, c.y, p);
            p = fmaf(xv[r].z, c.z, p);
            p = fmaf(xv[r].w, c.w, p);
            if (p > bestp[r]) { bestp[r] = p; bestk[r] = k; }  // strict '>': first index wins ties
        }
    }

#pragma unroll
    for (int r = 0; r < RPT; ++r) {
        reinterpret_cast<float4*>(out)[base + r * TPB] = sc[bestk[r]];  // 4KB LDS gather
    }
}

extern "C" void kernel_launch(void* const* d_in, const int* in_sizes, int n_in,
                              void* d_out, int out_size, void* d_ws, size_t ws_size,
                              hipStream_t stream) {
    const float* x      = (const float*)d_in[0];
    const float* center = (const float*)d_in[1];
    float* out = (float*)d_out;

    vq_main<<<NROWS / (TPB * RPT), TPB, 0, stream>>>(x, center, out);
}

// Round 3
// 28.072 us; speedup vs baseline: 1.5354x; 1.0191x over previous
//
#include <hip/hip_runtime.h>

#define KC 256                  // codebook size
#define NROWS (8*64*64*64/4)    // 524288 rows of dim 4
#define RPT 2                   // rows per thread  (4096 waves -> 4 waves/SIMD)
#define TPB 256                 // threads per block

// Per row: argmax_k (x . c_k - 0.5*||c_k||^2)  ==  argmin_k ||x - c_k||^2.
// Straight-through forward value is just the hard-assigned center.
__global__ __launch_bounds__(TPB) void vq_main(const float* __restrict__ x,
                                               const float* __restrict__ center,
                                               float* __restrict__ out) {
    __shared__ float4 sc[KC];   // codebook
    __shared__ float smh[KC];   // -0.5*||c||^2

    const int tid = threadIdx.x;
    {
        float4 c = reinterpret_cast<const float4*>(center)[tid];
        sc[tid] = c;
        smh[tid] = -0.5f * (c.x * c.x + c.y * c.y + c.z * c.z + c.w * c.w);
    }
    __syncthreads();

    const int base = blockIdx.x * (TPB * RPT) + tid;
    const float4* x4 = reinterpret_cast<const float4*>(x);

    float4 xv[RPT];
#pragma unroll
    for (int r = 0; r < RPT; ++r) xv[r] = x4[base + r * TPB];  // coalesced

    float bestp[RPT];
    int   bestk[RPT];
#pragma unroll
    for (int r = 0; r < RPT; ++r) { bestp[r] = -__builtin_inff(); bestk[r] = 0; }

#pragma unroll 8
    for (int k = 0; k < KC; ++k) {
        float4 c  = sc[k];      // uniform addr -> broadcast ds_read_b128
        float  mh = smh[k];     // uniform addr -> broadcast ds_read_b32
#pragma unroll
        for (int r = 0; r < RPT; ++r) {
            float p = fmaf(xv[r].x, c.x, mh);
            p = fmaf(xv[r].y, c.y, p);
            p = fmaf(xv[r].z, c.z, p);
            p = fmaf(xv[r].w, c.w, p);
            if (p > bestp[r]) { bestp[r] = p; bestk[r] = k; }  // strict '>': first index wins ties
        }
    }

#pragma unroll
    for (int r = 0; r < RPT; ++r) {
        reinterpret_cast<float4*>(out)[base + r * TPB] = sc[bestk[r]];  // LDS gather
    }
}

extern "C" void kernel_launch(void* const* d_in, const int* in_sizes, int n_in,
                              void* d_out, int out_size, void* d_ws, size_t ws_size,
                              hipStream_t stream) {
    const float* x      = (const float*)d_in[0];
    const float* center = (const float*)d_in[1];
    float* out = (float*)d_out;

    vq_main<<<NROWS / (TPB * RPT), TPB, 0, stream>>>(x, center, out);
}